// Round 1
// baseline (3083.358 us; speedup 1.0000x reference)
//
#include <hip/hip_runtime.h>
#include <cstdint>
#include <cstddef>

#define NNODES 50000
#define NEDGES 20000
#define NNZT   1600000
#define CCAT   1024   // 4*256 concat features
#define CIN    256
#define COUT   40

// ---------------- CSR build ----------------

__global__ void count_k(const int* __restrict__ ni, const int* __restrict__ ei,
                        int* __restrict__ cnt_e, int* __restrict__ cnt_n) {
  int i = blockIdx.x * 256 + threadIdx.x;
  if (i < NNZT) {
    atomicAdd(&cnt_e[ei[i]], 1);
    atomicAdd(&cnt_n[ni[i]], 1);
  }
}

// single-block exclusive scan, 1024 threads, len <= ~64k
__global__ void scan_k(const int* __restrict__ cnt, int* __restrict__ off, int len) {
  __shared__ int sh[1024];
  int t = threadIdx.x;
  int C = (len + 1023) >> 10;
  int base = t * C;
  int s = 0;
  for (int j = 0; j < C; j++) { int i = base + j; if (i < len) s += cnt[i]; }
  sh[t] = s;
  __syncthreads();
  for (int d = 1; d < 1024; d <<= 1) {
    int v = (t >= d) ? sh[t - d] : 0;
    __syncthreads();
    sh[t] += v;
    __syncthreads();
  }
  int run = (t == 0) ? 0 : sh[t - 1];
  for (int j = 0; j < C; j++) {
    int i = base + j;
    if (i < len) { off[i] = run; run += cnt[i]; }
  }
  if (t == 1023) off[len] = sh[1023];
}

__global__ void fill_k(const int* __restrict__ ni, const int* __restrict__ ei,
                       const int* __restrict__ off_e, const int* __restrict__ off_n,
                       int* __restrict__ cur_e, int* __restrict__ cur_n,
                       int* __restrict__ adj_e, int* __restrict__ adj_n) {
  int i = blockIdx.x * 256 + threadIdx.x;
  if (i < NNZT) {
    int e = ei[i], n = ni[i];
    int p = atomicAdd(&cur_e[e], 1);
    adj_e[off_e[e] + p] = n;   // edge-CSR stores node ids
    int q = atomicAdd(&cur_n[n], 1);
    adj_n[off_n[n] + q] = e;   // node-CSR stores edge ids
  }
}

__global__ void deg_k(const int* __restrict__ off_e, const int* __restrict__ off_n,
                      float* __restrict__ de_inv, float* __restrict__ dv_is) {
  int i = blockIdx.x * 256 + threadIdx.x;
  if (i < NNODES) {
    int d = off_n[i + 1] - off_n[i];
    dv_is[i] = (d > 0) ? rsqrtf((float)d) : 0.f;
  }
  if (i < NEDGES) {
    int d = off_e[i + 1] - off_e[i];
    de_inv[i] = (d > 0) ? (1.f / (float)d) : 0.f;
  }
}

// ---------------- s1 = S * ones (for bias-through-smooth) ----------------

__global__ void t1_k(const int* __restrict__ off_e, const int* __restrict__ adj_e,
                     const float* __restrict__ dv_is, const float* __restrict__ de_inv,
                     float* __restrict__ t1) {
  int e = blockIdx.x; int lane = threadIdx.x;
  int beg = off_e[e], end = off_e[e + 1];
  float s = 0.f;
  for (int j = beg + lane; j < end; j += 64) s += dv_is[adj_e[j]];
  for (int d = 32; d > 0; d >>= 1) s += __shfl_down(s, d);
  if (lane == 0) t1[e] = s * de_inv[e];
}

__global__ void s1_k(const int* __restrict__ off_n, const int* __restrict__ adj_n,
                     const float* __restrict__ t1, const float* __restrict__ dv_is,
                     float* __restrict__ s1) {
  int n = blockIdx.x; int lane = threadIdx.x;
  int beg = off_n[n], end = off_n[n + 1];
  float s = 0.f;
  for (int j = beg + lane; j < end; j += 64) s += t1[adj_n[j]];
  for (int d = 32; d > 0; d >>= 1) s += __shfl_down(s, d);
  if (lane == 0) s1[n] = s * dv_is[n];
}

// ---------------- edge gather of x (all 4 branches = 1024 ch) ----------------
// ef[e][f] = de_inv[e] * sum_{n in edge e} dv_is[n] * x[br][n][c],  f = br*256+c

__global__ __launch_bounds__(256) void gatherx_k(
    const float* __restrict__ x, const int* __restrict__ off_e,
    const int* __restrict__ adj_e, const float* __restrict__ dv_is,
    const float* __restrict__ de_inv, float* __restrict__ ef) {
  int e = blockIdx.x;
  int t = threadIdx.x;
  int f = t * 4;
  const float* xb = x + (size_t)(f >> 8) * NNODES * CIN + (f & 255);
  float4 acc = {0.f, 0.f, 0.f, 0.f};
  __shared__ int   s_n[128];
  __shared__ float s_w[128];
  int beg = off_e[e], end = off_e[e + 1];
  for (int c0 = beg; c0 < end; c0 += 128) {
    int m = min(128, end - c0);
    if (t < m) { int n = adj_e[c0 + t]; s_n[t] = n; s_w[t] = dv_is[n]; }
    __syncthreads();
    #pragma unroll 4
    for (int j = 0; j < m; j++) {
      float4 xv = *(const float4*)(xb + (size_t)s_n[j] * CIN);
      float w = s_w[j];
      acc.x += w * xv.x; acc.y += w * xv.y; acc.z += w * xv.z; acc.w += w * xv.w;
    }
    __syncthreads();
  }
  float sc = de_inv[e];
  float4 o = {acc.x * sc, acc.y * sc, acc.z * sc, acc.w * sc};
  *(float4*)(ef + (size_t)e * CCAT + f) = o;
}

// ---------------- GEMM1: g[e][br*256+hid] = ef[e][br*256+:] @ W1[br] ----------------

__global__ __launch_bounds__(256) void gemm1_k(
    const float* __restrict__ A,   // ef [E][1024]
    const float* __restrict__ W1,  // [4][256][256]
    float* __restrict__ G) {       // [E][1024]
  int rb = blockIdx.x;  // row block (64 edges)
  int cb = blockIdx.y;  // col block (64 of 256)
  int br = blockIdx.z;  // branch
  int t = threadIdx.x;
  int tx = t & 15, ty = t >> 4;
  __shared__ float As[32][68];  // [k][row]
  __shared__ float Bs[32][64];  // [k][col]
  float acc[4][4] = {};
  int row0 = rb * 64;
  const float* Bp = W1 + (size_t)br * CIN * CIN + cb * 64;
  for (int k0 = 0; k0 < CIN; k0 += 32) {
    #pragma unroll
    for (int i = 0; i < 2; i++) {
      int l = i * 256 + t;           // 0..511 float4 index
      // A tile: 64 rows x 32 k
      int row = l >> 3, kv = l & 7;
      float4 v = {0.f, 0.f, 0.f, 0.f};
      int r = row0 + row;
      if (r < NEDGES) v = *(const float4*)(A + (size_t)r * CCAT + br * 256 + k0 + kv * 4);
      As[kv * 4 + 0][row] = v.x; As[kv * 4 + 1][row] = v.y;
      As[kv * 4 + 2][row] = v.z; As[kv * 4 + 3][row] = v.w;
      // B tile: 32 k x 64 cols
      int colv = l & 15, k = l >> 4;
      float4 b = *(const float4*)(Bp + (size_t)(k0 + k) * CIN + colv * 4);
      *(float4*)&Bs[k][colv * 4] = b;
    }
    __syncthreads();
    #pragma unroll
    for (int kk = 0; kk < 32; kk++) {
      float4 a = *(const float4*)&As[kk][ty * 4];
      float4 b = *(const float4*)&Bs[kk][tx * 4];
      acc[0][0] += a.x * b.x; acc[0][1] += a.x * b.y; acc[0][2] += a.x * b.z; acc[0][3] += a.x * b.w;
      acc[1][0] += a.y * b.x; acc[1][1] += a.y * b.y; acc[1][2] += a.y * b.z; acc[1][3] += a.y * b.w;
      acc[2][0] += a.z * b.x; acc[2][1] += a.z * b.y; acc[2][2] += a.z * b.z; acc[2][3] += a.z * b.w;
      acc[3][0] += a.w * b.x; acc[3][1] += a.w * b.y; acc[3][2] += a.w * b.z; acc[3][3] += a.w * b.w;
    }
    __syncthreads();
  }
  #pragma unroll
  for (int r = 0; r < 4; r++) {
    int row = row0 + ty * 4 + r;
    if (row < NEDGES) {
      float4 o = {acc[r][0], acc[r][1], acc[r][2], acc[r][3]};
      *(float4*)(G + (size_t)row * CCAT + br * 256 + cb * 64 + tx * 4) = o;
    }
  }
}

// ---------------- node scatter + bias + relu ----------------
// hidden[n][f] = relu(dv_is[n]*sum_{e in node n} g[e][f] + s1[n]*b1[f])

__global__ __launch_bounds__(256) void scatter_h_k(
    const float* __restrict__ G, const int* __restrict__ off_n,
    const int* __restrict__ adj_n, const float* __restrict__ dv_is,
    const float* __restrict__ s1, const float* __restrict__ b1,
    float* __restrict__ hidden) {
  int n = blockIdx.x, t = threadIdx.x, f = t * 4;
  __shared__ int s_e[128];
  float4 acc = {0.f, 0.f, 0.f, 0.f};
  int beg = off_n[n], end = off_n[n + 1];
  for (int c0 = beg; c0 < end; c0 += 128) {
    int m = min(128, end - c0);
    if (t < m) s_e[t] = adj_n[c0 + t];
    __syncthreads();
    #pragma unroll 4
    for (int j = 0; j < m; j++) {
      float4 gv = *(const float4*)(G + (size_t)s_e[j] * CCAT + f);
      acc.x += gv.x; acc.y += gv.y; acc.z += gv.z; acc.w += gv.w;
    }
    __syncthreads();
  }
  float w = dv_is[n], sb = s1[n];
  float4 bv = *(const float4*)(b1 + f);
  float4 h;
  h.x = fmaxf(w * acc.x + sb * bv.x, 0.f);
  h.y = fmaxf(w * acc.y + sb * bv.y, 0.f);
  h.z = fmaxf(w * acc.z + sb * bv.z, 0.f);
  h.w = fmaxf(w * acc.w + sb * bv.w, 0.f);
  *(float4*)(hidden + (size_t)n * CCAT + f) = h;
}

// ---------------- GEMM2: u[n][o] = hidden[n][:] @ W2 + b2 ----------------
// 256 rows/block; thread handles rows {r, r+128} x 20 cols.

__global__ __launch_bounds__(256) void gemm2_k(
    const float* __restrict__ H, const float* __restrict__ W2,
    const float* __restrict__ b2, float* __restrict__ U) {
  int nb = blockIdx.x;
  int t = threadIdx.x;
  int r = t & 127, ch = t >> 7;
  __shared__ float Hs[64][257];  // [k][row], padded
  __shared__ float Ws[64][40];   // [k][o]
  float acc0[20] = {}, acc1[20] = {};
  int n0 = nb * 256;
  for (int k0 = 0; k0 < CCAT; k0 += 64) {
    #pragma unroll
    for (int i = 0; i < 16; i++) {
      int l = i * 256 + t;       // float4 index, 4096 total
      int row = l >> 4, kv = l & 15;
      float4 v = {0.f, 0.f, 0.f, 0.f};
      int n = n0 + row;
      if (n < NNODES) v = *(const float4*)(H + (size_t)n * CCAT + k0 + kv * 4);
      Hs[kv * 4 + 0][row] = v.x; Hs[kv * 4 + 1][row] = v.y;
      Hs[kv * 4 + 2][row] = v.z; Hs[kv * 4 + 3][row] = v.w;
    }
    #pragma unroll
    for (int i = 0; i < 10; i++) {
      int l = i * 256 + t;       // 2560 total
      int k = l / 40, o = l - k * 40;
      Ws[k][o] = W2[(size_t)(k0 + k) * COUT + o];
    }
    __syncthreads();
    #pragma unroll 4
    for (int k = 0; k < 64; k++) {
      float h0 = Hs[k][r];
      float h1 = Hs[k][r + 128];
      const float* wr = &Ws[k][ch * 20];
      #pragma unroll
      for (int i = 0; i < 5; i++) {
        float4 wv = *(const float4*)(wr + i * 4);
        acc0[i * 4 + 0] += h0 * wv.x; acc0[i * 4 + 1] += h0 * wv.y;
        acc0[i * 4 + 2] += h0 * wv.z; acc0[i * 4 + 3] += h0 * wv.w;
        acc1[i * 4 + 0] += h1 * wv.x; acc1[i * 4 + 1] += h1 * wv.y;
        acc1[i * 4 + 2] += h1 * wv.z; acc1[i * 4 + 3] += h1 * wv.w;
      }
    }
    __syncthreads();
  }
  int n_a = n0 + r, n_b = n0 + r + 128;
  if (n_a < NNODES) {
    #pragma unroll
    for (int j = 0; j < 20; j++) {
      int o = ch * 20 + j;
      U[(size_t)n_a * COUT + o] = acc0[j] + b2[o];
    }
  }
  if (n_b < NNODES) {
    #pragma unroll
    for (int j = 0; j < 20; j++) {
      int o = ch * 20 + j;
      U[(size_t)n_b * COUT + o] = acc1[j] + b2[o];
    }
  }
}

// ---------------- final smooth (40 channels) ----------------

__global__ __launch_bounds__(256) void gather_u_k(
    const float* __restrict__ U, const int* __restrict__ off_e,
    const int* __restrict__ adj_e, const float* __restrict__ dv_is,
    const float* __restrict__ de_inv, float* __restrict__ ef2) {
  int e = blockIdx.x;
  int t = threadIdx.x;
  int w = t >> 6, lane = t & 63;
  __shared__ float red[4][COUT];
  float acc = 0.f;
  int beg = off_e[e], end = off_e[e + 1];
  if (lane < COUT) {
    for (int j = beg + w; j < end; j += 4) {
      int n = adj_e[j];
      acc += dv_is[n] * U[(size_t)n * COUT + lane];
    }
    red[w][lane] = acc;
  }
  __syncthreads();
  if (t < COUT) {
    float s = red[0][t] + red[1][t] + red[2][t] + red[3][t];
    ef2[(size_t)e * COUT + t] = s * de_inv[e];
  }
}

__global__ __launch_bounds__(256) void scatter_out_k(
    const float* __restrict__ ef2, const int* __restrict__ off_n,
    const int* __restrict__ adj_n, const float* __restrict__ dv_is,
    float* __restrict__ out) {
  int n = blockIdx.x;
  int t = threadIdx.x;
  int w = t >> 6, lane = t & 63;
  __shared__ float red[4][COUT];
  float acc = 0.f;
  int beg = off_n[n], end = off_n[n + 1];
  if (lane < COUT) {
    for (int j = beg + w; j < end; j += 4) {
      acc += ef2[(size_t)adj_n[j] * COUT + lane];
    }
    red[w][lane] = acc;
  }
  __syncthreads();
  if (t < COUT) {
    out[(size_t)n * COUT + t] = dv_is[n] * (red[0][t] + red[1][t] + red[2][t] + red[3][t]);
  }
}

// ---------------- launch ----------------

extern "C" void kernel_launch(void* const* d_in, const int* in_sizes, int n_in,
                              void* d_out, int out_size, void* d_ws, size_t ws_size,
                              hipStream_t stream) {
  const float* x  = (const float*)d_in[0];   // [4][50000][256]
  const float* W1 = (const float*)d_in[1];   // [4][256][256]
  const float* b1 = (const float*)d_in[2];   // [4][256] -> flat [1024]
  const float* W2 = (const float*)d_in[3];   // [1024][40]
  const float* b2 = (const float*)d_in[4];   // [40]
  const int* ni   = (const int*)d_in[5];     // node_idx [NNZ]
  const int* ei   = (const int*)d_in[6];     // edge_idx [NNZ]
  float* out = (float*)d_out;

  char* ws = (char*)d_ws;
  size_t o = 0;
  int* cnt_e = (int*)(ws + o); o += (size_t)NEDGES * 4;
  int* cnt_n = (int*)(ws + o); o += (size_t)NNODES * 4;
  int* cur_e = (int*)(ws + o); o += (size_t)NEDGES * 4;
  int* cur_n = (int*)(ws + o); o += (size_t)NNODES * 4;
  int* off_e = (int*)(ws + o); o += (size_t)(NEDGES + 1) * 4; o = (o + 255) & ~(size_t)255;
  int* off_n = (int*)(ws + o); o += (size_t)(NNODES + 1) * 4; o = (o + 255) & ~(size_t)255;
  float* de_inv = (float*)(ws + o); o += (size_t)NEDGES * 4;
  float* dv_is  = (float*)(ws + o); o += (size_t)NNODES * 4;
  float* t1     = (float*)(ws + o); o += (size_t)NEDGES * 4;
  float* s1     = (float*)(ws + o); o += (size_t)NNODES * 4; o = (o + 255) & ~(size_t)255;
  int* adj_e = (int*)(ws + o); o += (size_t)NNZT * 4;
  int* adj_n = (int*)(ws + o); o += (size_t)NNZT * 4; o = (o + 255) & ~(size_t)255;
  // region0: g [E][1024]; later reused for u [N][40] and ef2 [E][40]
  float* g  = (float*)(ws + o);
  float* u  = g;                                          // g dead before gemm2 writes u
  float* ef2 = (float*)((char*)g + (size_t)NNODES * COUT * 4);
  o += (size_t)NEDGES * CCAT * 4;
  // region1: ef_x [E][1024]; later overwritten by hidden [N][1024]
  float* ef_x   = (float*)(ws + o);
  float* hidden = ef_x;                                   // ef_x dead before scatter_h writes
  o += (size_t)NNODES * CCAT * 4;

  hipMemsetAsync(cnt_e, 0, (size_t)(NEDGES + NNODES) * 2 * sizeof(int), stream);
  count_k<<<(NNZT + 255) / 256, 256, 0, stream>>>(ni, ei, cnt_e, cnt_n);
  scan_k<<<1, 1024, 0, stream>>>(cnt_e, off_e, NEDGES);
  scan_k<<<1, 1024, 0, stream>>>(cnt_n, off_n, NNODES);
  fill_k<<<(NNZT + 255) / 256, 256, 0, stream>>>(ni, ei, off_e, off_n, cur_e, cur_n, adj_e, adj_n);
  deg_k<<<(NNODES + 255) / 256, 256, 0, stream>>>(off_e, off_n, de_inv, dv_is);
  t1_k<<<NEDGES, 64, 0, stream>>>(off_e, adj_e, dv_is, de_inv, t1);
  s1_k<<<NNODES, 64, 0, stream>>>(off_n, adj_n, t1, dv_is, s1);
  gatherx_k<<<NEDGES, 256, 0, stream>>>(x, off_e, adj_e, dv_is, de_inv, ef_x);
  gemm1_k<<<dim3((NEDGES + 63) / 64, 4, 4), 256, 0, stream>>>(ef_x, W1, g);
  scatter_h_k<<<NNODES, 256, 0, stream>>>(g, off_n, adj_n, dv_is, s1, b1, hidden);
  gemm2_k<<<(NNODES + 255) / 256, 256, 0, stream>>>(hidden, W2, b2, u);
  gather_u_k<<<NEDGES, 256, 0, stream>>>(u, off_e, adj_e, dv_is, de_inv, ef2);
  scatter_out_k<<<NNODES, 256, 0, stream>>>(ef2, off_n, adj_n, dv_is, out);
}

// Round 2
// 2003.378 us; speedup vs baseline: 1.5391x; 1.5391x over previous
//
#include <hip/hip_runtime.h>
#include <cstdint>
#include <cstddef>

#define NNODES 50000
#define NEDGES 20000
#define NNZT   1600000
#define CCAT   1024   // 4*256 concat features
#define CIN    256
#define COUT   40

typedef __attribute__((ext_vector_type(8))) short bf16x8;
typedef __attribute__((ext_vector_type(4))) float f32x4;

__device__ inline float bflo(unsigned u) { return __uint_as_float(u << 16); }
__device__ inline float bfhi(unsigned u) { return __uint_as_float(u & 0xffff0000u); }
__device__ inline unsigned short f2bf(float f) {
  unsigned u = __float_as_uint(f);
  u += 0x7fff + ((u >> 16) & 1);
  return (unsigned short)(u >> 16);
}

// ---------------- CSR build ----------------

__global__ void count_k(const int* __restrict__ ni, const int* __restrict__ ei,
                        int* __restrict__ cnt_e, int* __restrict__ cnt_n) {
  int i = blockIdx.x * 256 + threadIdx.x;
  if (i < NNZT) {
    atomicAdd(&cnt_e[ei[i]], 1);
    atomicAdd(&cnt_n[ni[i]], 1);
  }
}

// single-block exclusive scan, 1024 threads
__global__ void scan_k(const int* __restrict__ cnt, int* __restrict__ off, int len) {
  __shared__ int sh[1024];
  int t = threadIdx.x;
  int C = (len + 1023) >> 10;
  int base = t * C;
  int s = 0;
  for (int j = 0; j < C; j++) { int i = base + j; if (i < len) s += cnt[i]; }
  sh[t] = s;
  __syncthreads();
  for (int d = 1; d < 1024; d <<= 1) {
    int v = (t >= d) ? sh[t - d] : 0;
    __syncthreads();
    sh[t] += v;
    __syncthreads();
  }
  int run = (t == 0) ? 0 : sh[t - 1];
  for (int j = 0; j < C; j++) {
    int i = base + j;
    if (i < len) { off[i] = run; run += cnt[i]; }
  }
  if (t == 1023) off[len] = sh[1023];
}

__global__ void fill_k(const int* __restrict__ ni, const int* __restrict__ ei,
                       const int* __restrict__ off_e, const int* __restrict__ off_n,
                       int* __restrict__ cur_e, int* __restrict__ cur_n,
                       int* __restrict__ adj_e, int* __restrict__ adj_n) {
  int i = blockIdx.x * 256 + threadIdx.x;
  if (i < NNZT) {
    int e = ei[i], n = ni[i];
    int p = atomicAdd(&cur_e[e], 1);
    adj_e[off_e[e] + p] = n;
    int q = atomicAdd(&cur_n[n], 1);
    adj_n[off_n[n] + q] = e;
  }
}

__global__ void deg_k(const int* __restrict__ off_e, const int* __restrict__ off_n,
                      float* __restrict__ de_inv, float* __restrict__ dv_is) {
  int i = blockIdx.x * 256 + threadIdx.x;
  if (i < NNODES) {
    int d = off_n[i + 1] - off_n[i];
    dv_is[i] = (d > 0) ? rsqrtf((float)d) : 0.f;
  }
  if (i < NEDGES) {
    int d = off_e[i + 1] - off_e[i];
    de_inv[i] = (d > 0) ? (1.f / (float)d) : 0.f;
  }
}

// ---------------- s1 = S * ones (bias-through-smooth) ----------------

__global__ void t1_k(const int* __restrict__ off_e, const int* __restrict__ adj_e,
                     const float* __restrict__ dv_is, const float* __restrict__ de_inv,
                     float* __restrict__ t1) {
  int e = blockIdx.x; int lane = threadIdx.x;
  int beg = off_e[e], end = off_e[e + 1];
  float s = 0.f;
  for (int j = beg + lane; j < end; j += 64) s += dv_is[adj_e[j]];
  for (int d = 32; d > 0; d >>= 1) s += __shfl_down(s, d);
  if (lane == 0) t1[e] = s * de_inv[e];
}

__global__ void s1_k(const int* __restrict__ off_n, const int* __restrict__ adj_n,
                     const float* __restrict__ t1, const float* __restrict__ dv_is,
                     float* __restrict__ s1) {
  int n = blockIdx.x; int lane = threadIdx.x;
  int beg = off_n[n], end = off_n[n + 1];
  float s = 0.f;
  for (int j = beg + lane; j < end; j += 64) s += t1[adj_n[j]];
  for (int d = 32; d > 0; d >>= 1) s += __shfl_down(s, d);
  if (lane == 0) s1[n] = s * dv_is[n];
}

// ---------------- casts ----------------
// xb[n][br*256+c] = bf16(dv_is[n] * x[br][n][c])

__global__ __launch_bounds__(256) void castx_k(
    const float* __restrict__ x, const float* __restrict__ dv_is,
    unsigned short* __restrict__ xb) {
  int n = blockIdx.x;
  int t = threadIdx.x;
  int br = t >> 6, c4 = (t & 63) * 4;
  float dv = dv_is[n];
  float4 v = *(const float4*)(x + ((size_t)br * NNODES + n) * CIN + c4);
  ushort4 o;
  o.x = f2bf(v.x * dv); o.y = f2bf(v.y * dv);
  o.z = f2bf(v.z * dv); o.w = f2bf(v.w * dv);
  *(ushort4*)(xb + (size_t)n * CCAT + br * 256 + c4) = o;
}

// W1t[br][n][k] = bf16(W1[br][k][n])
__global__ __launch_bounds__(256) void castw1_k(
    const float* __restrict__ W1, unsigned short* __restrict__ W1t) {
  int n = blockIdx.x, br = blockIdx.y, t = threadIdx.x;
  float v = W1[((size_t)br * CIN + t) * CIN + n];
  W1t[((size_t)br * CIN + n) * CIN + t] = f2bf(v);
}

// ---------------- edge gather: ef[e][f] = de_inv[e]*sum xb[n][f] ----------------

__global__ __launch_bounds__(128) void gatherx_k(
    const unsigned short* __restrict__ xb, const int* __restrict__ off_e,
    const int* __restrict__ adj_e, const float* __restrict__ de_inv,
    unsigned short* __restrict__ ef) {
  int e = blockIdx.x;
  int t = threadIdx.x;
  int f = t * 8;
  float acc[8] = {};
  __shared__ int s_n[128];
  int beg = off_e[e], end = off_e[e + 1];
  for (int c0 = beg; c0 < end; c0 += 128) {
    int m = min(128, end - c0);
    if (t < m) s_n[t] = adj_e[c0 + t];
    __syncthreads();
    for (int j = 0; j < m; j++) {
      uint4 v = *(const uint4*)(xb + (size_t)s_n[j] * CCAT + f);
      acc[0] += bflo(v.x); acc[1] += bfhi(v.x);
      acc[2] += bflo(v.y); acc[3] += bfhi(v.y);
      acc[4] += bflo(v.z); acc[5] += bfhi(v.z);
      acc[6] += bflo(v.w); acc[7] += bfhi(v.w);
    }
    __syncthreads();
  }
  float sc = de_inv[e];
  uint4 o;
  o.x = (unsigned)f2bf(acc[0] * sc) | ((unsigned)f2bf(acc[1] * sc) << 16);
  o.y = (unsigned)f2bf(acc[2] * sc) | ((unsigned)f2bf(acc[3] * sc) << 16);
  o.z = (unsigned)f2bf(acc[4] * sc) | ((unsigned)f2bf(acc[5] * sc) << 16);
  o.w = (unsigned)f2bf(acc[6] * sc) | ((unsigned)f2bf(acc[7] * sc) << 16);
  *(uint4*)(ef + (size_t)e * CCAT + f) = o;
}

// ---------------- GEMM1 (MFMA bf16): g = ef @ W1, per branch ----------------

__global__ __launch_bounds__(256) void gemm1_k(
    const unsigned short* __restrict__ ef,   // [E][1024] bf16
    const unsigned short* __restrict__ W1t,  // [4][256(n)][256(k)] bf16
    unsigned short* __restrict__ G) {        // [E][1024] bf16
  int rb = blockIdx.x, cb = blockIdx.y, br = blockIdx.z;
  int t = threadIdx.x;
  int w = t >> 6, l = t & 63;
  __shared__ unsigned short As[64 * 40];  // 64 rows x 32 k, stride 40
  __shared__ unsigned short Bs[64 * 40];  // 64 cols x 32 k, stride 40
  f32x4 acc[4] = {};
  int row0 = rb * 64;
  int srow = t >> 2, seg = t & 3;
  bool aok = (row0 + srow) < NEDGES;
  const unsigned short* ap = ef + (size_t)(row0 + srow) * CCAT + br * 256 + seg * 8;
  const unsigned short* bp = W1t + ((size_t)br * CIN + cb * 64 + srow) * CIN + seg * 8;
  int m = l & 15, q = l >> 4;
  for (int k0 = 0; k0 < CIN; k0 += 32) {
    uint4 av = {0, 0, 0, 0};
    if (aok) av = *(const uint4*)(ap + k0);
    uint4 bv = *(const uint4*)(bp + k0);
    *(uint4*)&As[srow * 40 + seg * 8] = av;
    *(uint4*)&Bs[srow * 40 + seg * 8] = bv;
    __syncthreads();
    bf16x8 a = *(bf16x8*)&As[(w * 16 + m) * 40 + q * 8];
    #pragma unroll
    for (int c = 0; c < 4; c++) {
      bf16x8 b = *(bf16x8*)&Bs[(c * 16 + m) * 40 + q * 8];
      acc[c] = __builtin_amdgcn_mfma_f32_16x16x32_bf16(a, b, acc[c], 0, 0, 0);
    }
    __syncthreads();
  }
  #pragma unroll
  for (int c = 0; c < 4; c++) {
    #pragma unroll
    for (int r = 0; r < 4; r++) {
      int row = row0 + w * 16 + q * 4 + r;
      if (row < NEDGES)
        G[(size_t)row * CCAT + br * 256 + cb * 64 + c * 16 + m] = f2bf(acc[c][r]);
    }
  }
}

// ---------------- node scatter + bias + relu (bf16 out) ----------------

__global__ __launch_bounds__(128) void scatter_h_k(
    const unsigned short* __restrict__ G, const int* __restrict__ off_n,
    const int* __restrict__ adj_n, const float* __restrict__ dv_is,
    const float* __restrict__ s1, const float* __restrict__ b1,
    unsigned short* __restrict__ hidden) {
  int n = blockIdx.x, t = threadIdx.x, f = t * 8;
  __shared__ int s_e[128];
  float acc[8] = {};
  int beg = off_n[n], end = off_n[n + 1];
  for (int c0 = beg; c0 < end; c0 += 128) {
    int m = min(128, end - c0);
    if (t < m) s_e[t] = adj_n[c0 + t];
    __syncthreads();
    for (int j = 0; j < m; j++) {
      uint4 v = *(const uint4*)(G + (size_t)s_e[j] * CCAT + f);
      acc[0] += bflo(v.x); acc[1] += bfhi(v.x);
      acc[2] += bflo(v.y); acc[3] += bfhi(v.y);
      acc[4] += bflo(v.z); acc[5] += bfhi(v.z);
      acc[6] += bflo(v.w); acc[7] += bfhi(v.w);
    }
    __syncthreads();
  }
  float wv = dv_is[n], sb = s1[n];
  float4 b0 = *(const float4*)(b1 + f);
  float4 b4 = *(const float4*)(b1 + f + 4);
  float h[8];
  h[0] = fmaxf(wv * acc[0] + sb * b0.x, 0.f);
  h[1] = fmaxf(wv * acc[1] + sb * b0.y, 0.f);
  h[2] = fmaxf(wv * acc[2] + sb * b0.z, 0.f);
  h[3] = fmaxf(wv * acc[3] + sb * b0.w, 0.f);
  h[4] = fmaxf(wv * acc[4] + sb * b4.x, 0.f);
  h[5] = fmaxf(wv * acc[5] + sb * b4.y, 0.f);
  h[6] = fmaxf(wv * acc[6] + sb * b4.z, 0.f);
  h[7] = fmaxf(wv * acc[7] + sb * b4.w, 0.f);
  uint4 o;
  o.x = (unsigned)f2bf(h[0]) | ((unsigned)f2bf(h[1]) << 16);
  o.y = (unsigned)f2bf(h[2]) | ((unsigned)f2bf(h[3]) << 16);
  o.z = (unsigned)f2bf(h[4]) | ((unsigned)f2bf(h[5]) << 16);
  o.w = (unsigned)f2bf(h[6]) | ((unsigned)f2bf(h[7]) << 16);
  *(uint4*)(hidden + (size_t)n * CCAT + f) = o;
}

// ---------------- GEMM2: u[n][o] = hidden[n][:] @ W2 + b2 (fp32 acc) ----------------

__global__ __launch_bounds__(256) void gemm2_k(
    const unsigned short* __restrict__ H, const float* __restrict__ W2,
    const float* __restrict__ b2, float* __restrict__ U) {
  int nb = blockIdx.x;
  int t = threadIdx.x;
  int r = t & 127, ch = t >> 7;
  __shared__ float Hs[64][257];
  __shared__ float Ws[64][40];
  float acc0[20] = {}, acc1[20] = {};
  int n0 = nb * 256;
  for (int k0 = 0; k0 < CCAT; k0 += 64) {
    #pragma unroll
    for (int i = 0; i < 8; i++) {
      int li = i * 256 + t;        // 2048 uint4 loads
      int row = li >> 3, kv = li & 7;
      uint4 v = {0, 0, 0, 0};
      int n = n0 + row;
      if (n < NNODES) v = *(const uint4*)(H + (size_t)n * CCAT + k0 + kv * 8);
      int kb = kv * 8;
      Hs[kb + 0][row] = bflo(v.x); Hs[kb + 1][row] = bfhi(v.x);
      Hs[kb + 2][row] = bflo(v.y); Hs[kb + 3][row] = bfhi(v.y);
      Hs[kb + 4][row] = bflo(v.z); Hs[kb + 5][row] = bfhi(v.z);
      Hs[kb + 6][row] = bflo(v.w); Hs[kb + 7][row] = bfhi(v.w);
    }
    #pragma unroll
    for (int i = 0; i < 10; i++) {
      int li = i * 256 + t;        // 2560
      int k = li / 40, o2 = li - k * 40;
      Ws[k][o2] = W2[(size_t)(k0 + k) * COUT + o2];
    }
    __syncthreads();
    #pragma unroll 4
    for (int k = 0; k < 64; k++) {
      float h0 = Hs[k][r];
      float h1 = Hs[k][r + 128];
      const float* wr = &Ws[k][ch * 20];
      #pragma unroll
      for (int i = 0; i < 5; i++) {
        float4 wv = *(const float4*)(wr + i * 4);
        acc0[i * 4 + 0] += h0 * wv.x; acc0[i * 4 + 1] += h0 * wv.y;
        acc0[i * 4 + 2] += h0 * wv.z; acc0[i * 4 + 3] += h0 * wv.w;
        acc1[i * 4 + 0] += h1 * wv.x; acc1[i * 4 + 1] += h1 * wv.y;
        acc1[i * 4 + 2] += h1 * wv.z; acc1[i * 4 + 3] += h1 * wv.w;
      }
    }
    __syncthreads();
  }
  int n_a = n0 + r, n_b = n0 + r + 128;
  if (n_a < NNODES) {
    #pragma unroll
    for (int j = 0; j < 20; j++) {
      int o2 = ch * 20 + j;
      U[(size_t)n_a * COUT + o2] = acc0[j] + b2[o2];
    }
  }
  if (n_b < NNODES) {
    #pragma unroll
    for (int j = 0; j < 20; j++) {
      int o2 = ch * 20 + j;
      U[(size_t)n_b * COUT + o2] = acc1[j] + b2[o2];
    }
  }
}

// ---------------- final smooth (40 channels, fp32) ----------------

__global__ __launch_bounds__(256) void gather_u_k(
    const float* __restrict__ U, const int* __restrict__ off_e,
    const int* __restrict__ adj_e, const float* __restrict__ dv_is,
    const float* __restrict__ de_inv, float* __restrict__ ef2) {
  int e = blockIdx.x;
  int t = threadIdx.x;
  int w = t >> 6, lane = t & 63;
  __shared__ float red[4][COUT];
  float acc = 0.f;
  int beg = off_e[e], end = off_e[e + 1];
  if (lane < COUT) {
    for (int j = beg + w; j < end; j += 4) {
      int n = adj_e[j];
      acc += dv_is[n] * U[(size_t)n * COUT + lane];
    }
    red[w][lane] = acc;
  }
  __syncthreads();
  if (t < COUT) {
    float s = red[0][t] + red[1][t] + red[2][t] + red[3][t];
    ef2[(size_t)e * COUT + t] = s * de_inv[e];
  }
}

__global__ __launch_bounds__(256) void scatter_out_k(
    const float* __restrict__ ef2, const int* __restrict__ off_n,
    const int* __restrict__ adj_n, const float* __restrict__ dv_is,
    float* __restrict__ out) {
  int n = blockIdx.x;
  int t = threadIdx.x;
  int w = t >> 6, lane = t & 63;
  __shared__ float red[4][COUT];
  float acc = 0.f;
  int beg = off_n[n], end = off_n[n + 1];
  if (lane < COUT) {
    for (int j = beg + w; j < end; j += 4) {
      acc += ef2[(size_t)adj_n[j] * COUT + lane];
    }
    red[w][lane] = acc;
  }
  __syncthreads();
  if (t < COUT) {
    out[(size_t)n * COUT + t] = dv_is[n] * (red[0][t] + red[1][t] + red[2][t] + red[3][t]);
  }
}

// ---------------- launch ----------------

extern "C" void kernel_launch(void* const* d_in, const int* in_sizes, int n_in,
                              void* d_out, int out_size, void* d_ws, size_t ws_size,
                              hipStream_t stream) {
  const float* x  = (const float*)d_in[0];   // [4][50000][256]
  const float* W1 = (const float*)d_in[1];   // [4][256][256]
  const float* b1 = (const float*)d_in[2];   // [4][256] flat
  const float* W2 = (const float*)d_in[3];   // [1024][40]
  const float* b2 = (const float*)d_in[4];   // [40]
  const int* ni   = (const int*)d_in[5];
  const int* ei   = (const int*)d_in[6];
  float* out = (float*)d_out;

  char* ws = (char*)d_ws;
  size_t o = 0;
  int* cnt_e = (int*)(ws + o); o += (size_t)NEDGES * 4;
  int* cnt_n = (int*)(ws + o); o += (size_t)NNODES * 4;
  int* cur_e = (int*)(ws + o); o += (size_t)NEDGES * 4;
  int* cur_n = (int*)(ws + o); o += (size_t)NNODES * 4;
  int* off_e = (int*)(ws + o); o += (size_t)(NEDGES + 1) * 4; o = (o + 255) & ~(size_t)255;
  int* off_n = (int*)(ws + o); o += (size_t)(NNODES + 1) * 4; o = (o + 255) & ~(size_t)255;
  float* de_inv = (float*)(ws + o); o += (size_t)NEDGES * 4;
  float* dv_is  = (float*)(ws + o); o += (size_t)NNODES * 4;
  float* t1     = (float*)(ws + o); o += (size_t)NEDGES * 4;
  float* s1     = (float*)(ws + o); o += (size_t)NNODES * 4; o = (o + 255) & ~(size_t)255;
  int* adj_e = (int*)(ws + o); o += (size_t)NNZT * 4;
  int* adj_n = (int*)(ws + o); o += (size_t)NNZT * 4; o = (o + 255) & ~(size_t)255;
  unsigned short* W1t = (unsigned short*)(ws + o); o += (size_t)4 * CIN * CIN * 2; o = (o + 255) & ~(size_t)255;
  // regionA: xb [N][1024] bf16, later reused as hidden (xb dead after gatherx)
  unsigned short* xb     = (unsigned short*)(ws + o);
  unsigned short* hidden = xb;
  o += (size_t)NNODES * CCAT * 2; o = (o + 255) & ~(size_t)255;
  // regionB: ef [E][1024] bf16; later u [N][40] f32 + ef2 [E][40] f32 (ef dead after gemm1)
  unsigned short* ef = (unsigned short*)(ws + o);
  float* u   = (float*)ef;
  float* ef2 = (float*)((char*)ef + (size_t)NNODES * COUT * 4);
  o += (size_t)NEDGES * CCAT * 2; o = (o + 255) & ~(size_t)255;
  // regionC: g [E][1024] bf16
  unsigned short* g = (unsigned short*)(ws + o);
  o += (size_t)NEDGES * CCAT * 2;

  hipMemsetAsync(cnt_e, 0, (size_t)(NEDGES + NNODES) * 2 * sizeof(int), stream);
  count_k<<<(NNZT + 255) / 256, 256, 0, stream>>>(ni, ei, cnt_e, cnt_n);
  scan_k<<<1, 1024, 0, stream>>>(cnt_e, off_e, NEDGES);
  scan_k<<<1, 1024, 0, stream>>>(cnt_n, off_n, NNODES);
  fill_k<<<(NNZT + 255) / 256, 256, 0, stream>>>(ni, ei, off_e, off_n, cur_e, cur_n, adj_e, adj_n);
  deg_k<<<(NNODES + 255) / 256, 256, 0, stream>>>(off_e, off_n, de_inv, dv_is);
  castx_k<<<NNODES, 256, 0, stream>>>(x, dv_is, xb);
  castw1_k<<<dim3(CIN, 4), 256, 0, stream>>>(W1, W1t);
  t1_k<<<NEDGES, 64, 0, stream>>>(off_e, adj_e, dv_is, de_inv, t1);
  s1_k<<<NNODES, 64, 0, stream>>>(off_n, adj_n, t1, dv_is, s1);
  gatherx_k<<<NEDGES, 128, 0, stream>>>(xb, off_e, adj_e, de_inv, ef);
  gemm1_k<<<dim3((NEDGES + 63) / 64, 4, 4), 256, 0, stream>>>(ef, W1t, g);
  scatter_h_k<<<NNODES, 128, 0, stream>>>(g, off_n, adj_n, dv_is, s1, b1, hidden);
  gemm2_k<<<(NNODES + 255) / 256, 256, 0, stream>>>(hidden, W2, b2, u);
  gather_u_k<<<NEDGES, 256, 0, stream>>>(u, off_e, adj_e, dv_is, de_inv, ef2);
  scatter_out_k<<<NNODES, 256, 0, stream>>>(ef2, off_n, adj_n, dv_is, out);
}